// Round 3
// baseline (309.605 us; speedup 1.0000x reference)
//
#include <hip/hip_runtime.h>
#include <hip/hip_bf16.h>

// GraphSAGE (2x SAGEConv mean + normalize + relu, final linear) on MI355X.
// R18: kernel-count and phase reduction.
//  - partitionA: direct global scatter (no pk LDS staging, no scan, no
//    copy-out; 2 barriers). 512-thread blocks, CHA=8192 -> 4 blocks/CU.
//    cvt_x_bf16 fused in as a grid-stride prologue. bcursor init via
//    hipMemsetAsync (bcursor now holds per-bucket COUNTS, base = b*CAPH).
//  - gather32_p1 + dense2 fused into gather32p1_dense2 (kills agg2b
//    round-trip, one less launch). p0/p1 L2-residency split preserved.
//  - Pipeline: memset + 5 kernels (was 7 kernels). ~70 us of the 276 was
//    unattributed inter-dispatch gap; fewer launches attacks that directly.

#define CHA 8192    // edges per phase-A block
#define MAXBH 800   // max half-buckets (NBH = ceil(N/128) = 782)
#define CAPH 9728   // slots per 128-node half-bucket region (mean ~8.2K, ~17 sigma)

static __device__ __forceinline__ unsigned short f2bf(float f) {
    unsigned u = __float_as_uint(f);
    unsigned r = (u + 0x7FFFu + ((u >> 16) & 1u)) >> 16;   // RTN-even
    return (unsigned short)r;
}
#define BF_LO(u) __uint_as_float((u) << 16)
#define BF_HI(u) __uint_as_float((u) & 0xFFFF0000u)

// Phase A: per-block LDS histogram over 782 half-buckets (dst>>7) for ranks,
// one bcursor atomic per (block,bucket) to reserve a run, then DIRECT global
// scatter of packed edges to part[b*CAPH + base + rank]. Runs are address-
// contiguous so L2 assembles full lines. Also converts x -> xb bf16 (fused).
__global__ __launch_bounds__(512) void partitionA(
        const float* __restrict__ x, unsigned short* __restrict__ xb,
        const int* __restrict__ src, const int* __restrict__ dst,
        int* __restrict__ bcursor, unsigned* __restrict__ part,
        int E, int N, int NBH) {
    __shared__ int h[MAXBH], gb[MAXBH];                // 6.4 KB
    int t = threadIdx.x;
    int base = blockIdx.x * CHA;
    int end = base + CHA; if (end > E) end = E;
    int cnt = end - base;

    // fused cvt_x: x [N x 14] fp32 -> xb [N x 16] bf16 (rows padded to 32B)
    for (int i = blockIdx.x * 512 + t; i < N * 16; i += gridDim.x * 512) {
        int n = i >> 4, f = i & 15;
        float v = (f < 14) ? x[n * 14 + f] : 0.f;
        xb[i] = f2bf(v);
    }

    int ed[16], es[16], er[16];
    for (int i = t; i < NBH; i += 512) h[i] = 0;
    __syncthreads();
    #pragma unroll
    for (int i = 0; i < 4; ++i) {
        int j = i * 2048 + t * 4;
        if (j + 4 <= cnt) {
            int4 d4 = *(const int4*)(dst + base + j);
            int4 s4 = *(const int4*)(src + base + j);
            ed[i*4+0] = d4.x; ed[i*4+1] = d4.y; ed[i*4+2] = d4.z; ed[i*4+3] = d4.w;
            es[i*4+0] = s4.x; es[i*4+1] = s4.y; es[i*4+2] = s4.z; es[i*4+3] = s4.w;
            er[i*4+0] = atomicAdd(&h[d4.x >> 7], 1);
            er[i*4+1] = atomicAdd(&h[d4.y >> 7], 1);
            er[i*4+2] = atomicAdd(&h[d4.z >> 7], 1);
            er[i*4+3] = atomicAdd(&h[d4.w >> 7], 1);
        } else {
            #pragma unroll
            for (int k = 0; k < 4; ++k) {
                if (j + k < cnt) {
                    ed[i*4+k] = dst[base + j + k];
                    es[i*4+k] = src[base + j + k];
                    er[i*4+k] = atomicAdd(&h[ed[i*4+k] >> 7], 1);
                } else ed[i*4+k] = -1;
            }
        }
    }
    __syncthreads();
    // reserve one run per non-empty bucket; bcursor holds counts (base 0)
    for (int i = t; i < NBH; i += 512) {
        int v = h[i];
        gb[i] = v ? atomicAdd(&bcursor[i], v) : 0;
    }
    __syncthreads();
    // direct scatter: store-and-forget, contiguous per (block,bucket) run
    #pragma unroll
    for (int i = 0; i < 16; ++i) {
        int dd = ed[i];
        if (dd >= 0) {
            int b = dd >> 7;
            int pos = gb[b] + er[i];
            if (pos < CAPH)                            // overflow guard (never hit)
                part[(size_t)b * CAPH + pos] =
                    ((unsigned)(dd & 127) << 24) | (unsigned)es[i];
        }
    }
}

// Phase B sort: 256-key counting sort (key = dstLocal7*2 + (src>=HALF)),
// ranks from histogram atomics; sorted_src written linearly; per-node meta
// (deg/offs/nlo) written.
__global__ __launch_bounds__(1024) void partitionB_sort(
        const unsigned* __restrict__ part, const int* __restrict__ bcursor,
        int* __restrict__ deg, int* __restrict__ offs, int* __restrict__ nlo,
        int* __restrict__ sorted_src, int N, int HALF) {
    __shared__ int pk2[CAPH];                          // 38 KB staging
    __shared__ int hh[256], keyofs[256];
    __shared__ int sTot;
    int hbid = blockIdx.x;
    int t = threadIdx.x;
    int start = hbid * CAPH;
    int cc = bcursor[hbid];                            // per-bucket COUNT now
    if (cc > CAPH) cc = CAPH;
    int end = start + cc;
    unsigned ce[10];
    int rk[10];
    if (t < 256) hh[t] = 0;
    __syncthreads();
    #pragma unroll
    for (int i = 0; i < 10; ++i) {
        int idx = start + t + i * 1024;
        unsigned p = 0xFFFFFFFFu;
        int r = 0;
        if (idx < end) {
            p = part[idx];
            int key = (int)(p >> 24) * 2 + (((int)(p & 0xFFFFFFu) < HALF) ? 0 : 1);
            r = atomicAdd(&hh[key], 1);
        }
        ce[i] = p;
        rk[i] = r;
    }
    __syncthreads();
    // wave-0 scan over the 256 keys (4/lane + shfl): writes keyofs = exclusive
    if (t < 64) {
        int b4 = t * 4;
        int v0 = hh[b4], v1 = hh[b4 + 1], v2 = hh[b4 + 2], v3 = hh[b4 + 3];
        int s1 = v0 + v1, s2 = s1 + v2, s3 = s2 + v3;
        int sc = s3;
        #pragma unroll
        for (int off = 1; off < 64; off <<= 1) {
            int nv = __shfl_up(sc, off);
            if (t >= off) sc += nv;
        }
        int excl = sc - s3;
        keyofs[b4]     = excl;
        keyofs[b4 + 1] = excl + v0;
        keyofs[b4 + 2] = excl + s1;
        keyofs[b4 + 3] = excl + s2;
        if (t == 63) sTot = excl + s3;
    }
    __syncthreads();
    if (t < 128) {
        int lo = hh[2 * t];
        int d = lo + hh[2 * t + 1];
        int excl = keyofs[2 * t];
        int node = hbid * 128 + t;
        if (node < N) {
            deg[node] = d;
            offs[node] = start + excl;
            nlo[node] = lo;
        }
    }
    #pragma unroll
    for (int i = 0; i < 10; ++i) {
        unsigned p = ce[i];
        if (p != 0xFFFFFFFFu) {
            int s = (int)(p & 0xFFFFFFu);
            int key = (int)(p >> 24) * 2 + ((s < HALF) ? 0 : 1);
            int pos = keyofs[key] + rk[i];
            if (pos < CAPH) pk2[pos] = s;
        }
    }
    __syncthreads();
    int tot = sTot; if (tot > CAPH) tot = CAPH;
    for (int i = t; i < tot; i += 1024)
        sorted_src[start + i] = pk2[i];
}

// Layer-1 gather + dense1 + normalize + relu. 256 threads = 32 nodes x
// 8 threads (4 edge-streams x 2 row-halves). All cross-thread exchange via
// __shfl within the aligned 8-lane node group.
__global__ __launch_bounds__(256) void gather14_dense1(
        const uint4* __restrict__ xb4, const float* __restrict__ x,
        const int* __restrict__ sorted_src, const int* __restrict__ offs,
        const int* __restrict__ deg,
        const float* __restrict__ W1l, const float* __restrict__ b1,
        const float* __restrict__ W1r,
        float* __restrict__ hbuf, unsigned short* __restrict__ hb, int N) {
    __shared__ float swl[448], swr[448], sb1[32];
    int t = threadIdx.x;
    for (int i = t; i < 448; i += 256) { swl[i] = W1l[i]; swr[i] = W1r[i]; }
    if (t < 32) sb1[t] = b1[t];
    __syncthreads();

    int node = blockIdx.x * 32 + (t >> 3);
    int sub = t & 7, ep = sub >> 1, half = sub & 1;
    int lanebase = (t & 63) & ~7;                      // node group base lane
    bool valid = node < N;
    int js = valid ? offs[node] : 0;
    int d  = valid ? deg[node] : 0;
    int je = js + d;
    float x0 = 0.f, x1 = 0.f;
    if (valid && sub < 7) {
        x0 = x[node * 14 + sub * 2];
        x1 = x[node * 14 + sub * 2 + 1];
    }

    float a[8] = {0,0,0,0,0,0,0,0};
    int j = js + ep;
    for (; j + 12 < je; j += 16) {                     // 4 edges/iter per stream
        int s0 = sorted_src[j], s1 = sorted_src[j + 4];
        int s2 = sorted_src[j + 8], s3 = sorted_src[j + 12];
        uint4 u0 = xb4[s0 * 2 + half], u1 = xb4[s1 * 2 + half];
        uint4 u2 = xb4[s2 * 2 + half], u3 = xb4[s3 * 2 + half];
        a[0] += (BF_LO(u0.x) + BF_LO(u1.x)) + (BF_LO(u2.x) + BF_LO(u3.x));
        a[1] += (BF_HI(u0.x) + BF_HI(u1.x)) + (BF_HI(u2.x) + BF_HI(u3.x));
        a[2] += (BF_LO(u0.y) + BF_LO(u1.y)) + (BF_LO(u2.y) + BF_LO(u3.y));
        a[3] += (BF_HI(u0.y) + BF_HI(u1.y)) + (BF_HI(u2.y) + BF_HI(u3.y));
        a[4] += (BF_LO(u0.z) + BF_LO(u1.z)) + (BF_LO(u2.z) + BF_LO(u3.z));
        a[5] += (BF_HI(u0.z) + BF_HI(u1.z)) + (BF_HI(u2.z) + BF_HI(u3.z));
        a[6] += (BF_LO(u0.w) + BF_LO(u1.w)) + (BF_LO(u2.w) + BF_LO(u3.w));
        a[7] += (BF_HI(u0.w) + BF_HI(u1.w)) + (BF_HI(u2.w) + BF_HI(u3.w));
    }
    for (; j + 4 < je; j += 8) {                       // 2 edges/iter per stream
        int s0 = sorted_src[j], s1 = sorted_src[j + 4];
        uint4 u0 = xb4[s0 * 2 + half], u1 = xb4[s1 * 2 + half];
        a[0] += BF_LO(u0.x) + BF_LO(u1.x);
        a[1] += BF_HI(u0.x) + BF_HI(u1.x);
        a[2] += BF_LO(u0.y) + BF_LO(u1.y);
        a[3] += BF_HI(u0.y) + BF_HI(u1.y);
        a[4] += BF_LO(u0.z) + BF_LO(u1.z);
        a[5] += BF_HI(u0.z) + BF_HI(u1.z);
        a[6] += BF_LO(u0.w) + BF_LO(u1.w);
        a[7] += BF_HI(u0.w) + BF_HI(u1.w);
    }
    for (; j < je; j += 4) {
        uint4 u0 = xb4[sorted_src[j] * 2 + half];
        a[0] += BF_LO(u0.x); a[1] += BF_HI(u0.x);
        a[2] += BF_LO(u0.y); a[3] += BF_HI(u0.y);
        a[4] += BF_LO(u0.z); a[5] += BF_HI(u0.z);
        a[6] += BF_LO(u0.w); a[7] += BF_HI(u0.w);
    }
    #pragma unroll
    for (int i = 0; i < 8; ++i) {
        a[i] += __shfl_xor(a[i], 2);                  // merge stream pairs
        a[i] += __shfl_xor(a[i], 4);                  // merge all 4 streams
    }

    // ---- dense1: each of 8 threads/node computes 4 of 32 outputs
    float inv = 1.0f / ((d > 0) ? (float)d : 1.0f);
    float acc[4];
    #pragma unroll
    for (int i = 0; i < 4; ++i) acc[i] = sb1[sub * 4 + i];
    #pragma unroll
    for (int k = 0; k < 14; ++k) {
        float ag = __shfl(a[k & 7], lanebase + (k >> 3)) * inv;   // half = k>=8
        float xv = __shfl((k & 1) ? x1 : x0, lanebase + (k >> 1));
        float4 wl = *(const float4*)&swl[k * 32 + sub * 4];
        float4 wr = *(const float4*)&swr[k * 32 + sub * 4];
        acc[0] += ag * wl.x + xv * wr.x;
        acc[1] += ag * wl.y + xv * wr.y;
        acc[2] += ag * wl.z + xv * wr.z;
        acc[3] += ag * wl.w + xv * wr.w;
    }
    float ss = 0.f;
    #pragma unroll
    for (int i = 0; i < 4; ++i) ss += acc[i] * acc[i];
    ss += __shfl_xor(ss, 1); ss += __shfl_xor(ss, 2); ss += __shfl_xor(ss, 4);
    float invn = 1.f / fmaxf(sqrtf(ss), 1e-12f);
    if (valid) {
        float hv[4];
        #pragma unroll
        for (int i = 0; i < 4; ++i) hv[i] = fmaxf(acc[i] * invn, 0.f);
        *(float4*)(hbuf + (size_t)node * 32 + sub * 4) =
            make_float4(hv[0], hv[1], hv[2], hv[3]);
        uint2 pb;
        pb.x = (unsigned)f2bf(hv[0]) | ((unsigned)f2bf(hv[1]) << 16);
        pb.y = (unsigned)f2bf(hv[2]) | ((unsigned)f2bf(hv[3]) << 16);
        *(uint2*)(hb + (size_t)node * 32 + sub * 4) = pb;
    }
}

// Layer-2 gather pass 0 (src < HALF; table half L2-resident): 8-deep unroll,
// writes RAW sums to agg2a.
__global__ __launch_bounds__(256) void gather32_p0(
        const uint4* __restrict__ hb, const int* __restrict__ sorted_src,
        const int* __restrict__ offs, const int* __restrict__ nlo,
        float4* __restrict__ agg2a, int N) {
    int idx = blockIdx.x * blockDim.x + threadIdx.x;
    int n = idx >> 2;
    if (n >= N) return;
    int q = idx & 3;
    int start = offs[n];
    int jend = nlo[n];
    float a0=0,a1=0,a2=0,a3=0,a4=0,a5=0,a6=0,a7=0;
    int j = 0;
    for (; j + 8 <= jend; j += 8) {
        int s0 = sorted_src[start + j + 0];
        int s1 = sorted_src[start + j + 1];
        int s2 = sorted_src[start + j + 2];
        int s3 = sorted_src[start + j + 3];
        int s4 = sorted_src[start + j + 4];
        int s5 = sorted_src[start + j + 5];
        int s6 = sorted_src[start + j + 6];
        int s7 = sorted_src[start + j + 7];
        uint4 u0 = hb[s0 * 4 + q];
        uint4 u1 = hb[s1 * 4 + q];
        uint4 u2 = hb[s2 * 4 + q];
        uint4 u3 = hb[s3 * 4 + q];
        uint4 u4 = hb[s4 * 4 + q];
        uint4 u5 = hb[s5 * 4 + q];
        uint4 u6 = hb[s6 * 4 + q];
        uint4 u7 = hb[s7 * 4 + q];
        a0 += (BF_LO(u0.x)+BF_LO(u1.x)+BF_LO(u2.x)+BF_LO(u3.x))
            + (BF_LO(u4.x)+BF_LO(u5.x)+BF_LO(u6.x)+BF_LO(u7.x));
        a1 += (BF_HI(u0.x)+BF_HI(u1.x)+BF_HI(u2.x)+BF_HI(u3.x))
            + (BF_HI(u4.x)+BF_HI(u5.x)+BF_HI(u6.x)+BF_HI(u7.x));
        a2 += (BF_LO(u0.y)+BF_LO(u1.y)+BF_LO(u2.y)+BF_LO(u3.y))
            + (BF_LO(u4.y)+BF_LO(u5.y)+BF_LO(u6.y)+BF_LO(u7.y));
        a3 += (BF_HI(u0.y)+BF_HI(u1.y)+BF_HI(u2.y)+BF_HI(u3.y))
            + (BF_HI(u4.y)+BF_HI(u5.y)+BF_HI(u6.y)+BF_HI(u7.y));
        a4 += (BF_LO(u0.z)+BF_LO(u1.z)+BF_LO(u2.z)+BF_LO(u3.z))
            + (BF_LO(u4.z)+BF_LO(u5.z)+BF_LO(u6.z)+BF_LO(u7.z));
        a5 += (BF_HI(u0.z)+BF_HI(u1.z)+BF_HI(u2.z)+BF_HI(u3.z))
            + (BF_HI(u4.z)+BF_HI(u5.z)+BF_HI(u6.z)+BF_HI(u7.z));
        a6 += (BF_LO(u0.w)+BF_LO(u1.w)+BF_LO(u2.w)+BF_LO(u3.w))
            + (BF_LO(u4.w)+BF_LO(u5.w)+BF_LO(u6.w)+BF_LO(u7.w));
        a7 += (BF_HI(u0.w)+BF_HI(u1.w)+BF_HI(u2.w)+BF_HI(u3.w))
            + (BF_HI(u4.w)+BF_HI(u5.w)+BF_HI(u6.w)+BF_HI(u7.w));
    }
    for (; j + 4 <= jend; j += 4) {
        int s0 = sorted_src[start + j + 0];
        int s1 = sorted_src[start + j + 1];
        int s2 = sorted_src[start + j + 2];
        int s3 = sorted_src[start + j + 3];
        uint4 u0 = hb[s0 * 4 + q];
        uint4 u1 = hb[s1 * 4 + q];
        uint4 u2 = hb[s2 * 4 + q];
        uint4 u3 = hb[s3 * 4 + q];
        a0 += BF_LO(u0.x)+BF_LO(u1.x)+BF_LO(u2.x)+BF_LO(u3.x);
        a1 += BF_HI(u0.x)+BF_HI(u1.x)+BF_HI(u2.x)+BF_HI(u3.x);
        a2 += BF_LO(u0.y)+BF_LO(u1.y)+BF_LO(u2.y)+BF_LO(u3.y);
        a3 += BF_HI(u0.y)+BF_HI(u1.y)+BF_HI(u2.y)+BF_HI(u3.y);
        a4 += BF_LO(u0.z)+BF_LO(u1.z)+BF_LO(u2.z)+BF_LO(u3.z);
        a5 += BF_HI(u0.z)+BF_HI(u1.z)+BF_HI(u2.z)+BF_HI(u3.z);
        a6 += BF_LO(u0.w)+BF_LO(u1.w)+BF_LO(u2.w)+BF_LO(u3.w);
        a7 += BF_HI(u0.w)+BF_HI(u1.w)+BF_HI(u2.w)+BF_HI(u3.w);
    }
    for (; j < jend; ++j) {
        uint4 u0 = hb[sorted_src[start + j] * 4 + q];
        a0 += BF_LO(u0.x); a1 += BF_HI(u0.x);
        a2 += BF_LO(u0.y); a3 += BF_HI(u0.y);
        a4 += BF_LO(u0.z); a5 += BF_HI(u0.z);
        a6 += BF_LO(u0.w); a7 += BF_HI(u0.w);
    }
    agg2a[n * 8 + q * 2 + 0] = make_float4(a0, a1, a2, a3);
    agg2a[n * 8 + q * 2 + 1] = make_float4(a4, a5, a6, a7);
}

// Layer-2 gather pass 1 (src >= HALF) FUSED with dense2 + final linear.
// 256 threads = 64 nodes x 4 lanes (q = feature quarter). After the hi-gather,
// merge with agg2a raw sums, apply 1/deg, stage node rows in LDS, then the
// dense2 matmul + L2-normalize + relu + final 32x2 linear, write out.
__global__ __launch_bounds__(256) void gather32p1_dense2(
        const uint4* __restrict__ hb, const int* __restrict__ sorted_src,
        const int* __restrict__ offs, const int* __restrict__ deg,
        const int* __restrict__ nlo, const float* __restrict__ agg2a,
        const float* __restrict__ hbuf,
        const float* __restrict__ W2l, const float* __restrict__ b2,
        const float* __restrict__ W2r, const float* __restrict__ Wlin,
        const float* __restrict__ blin, float* __restrict__ out, int N) {
    __shared__ float sa[64 * 33];                      // merged mean-agg rows
    __shared__ float sh2[64 * 33];                     // h rows
    __shared__ float swl[1024], swr[1024], swo[64], sb[32], sbo[2];
    int t = threadIdx.x;
    for (int i = t; i < 1024; i += 256) { swl[i] = W2l[i]; swr[i] = W2r[i]; }
    if (t < 64) swo[t] = Wlin[t];
    if (t < 32) sb[t] = b2[t];
    if (t < 2) sbo[t] = blin[t];

    int row = t >> 2, q = t & 3;
    int n = blockIdx.x * 64 + row;
    bool valid = n < N;
    int start = valid ? offs[n] : 0;
    int d = valid ? deg[n] : 0;
    int j = valid ? nlo[n] : 0;
    float a0=0,a1=0,a2=0,a3=0,a4=0,a5=0,a6=0,a7=0;
    for (; j + 8 <= d; j += 8) {
        int s0 = sorted_src[start + j + 0];
        int s1 = sorted_src[start + j + 1];
        int s2 = sorted_src[start + j + 2];
        int s3 = sorted_src[start + j + 3];
        int s4 = sorted_src[start + j + 4];
        int s5 = sorted_src[start + j + 5];
        int s6 = sorted_src[start + j + 6];
        int s7 = sorted_src[start + j + 7];
        uint4 u0 = hb[s0 * 4 + q];
        uint4 u1 = hb[s1 * 4 + q];
        uint4 u2 = hb[s2 * 4 + q];
        uint4 u3 = hb[s3 * 4 + q];
        uint4 u4 = hb[s4 * 4 + q];
        uint4 u5 = hb[s5 * 4 + q];
        uint4 u6 = hb[s6 * 4 + q];
        uint4 u7 = hb[s7 * 4 + q];
        a0 += (BF_LO(u0.x)+BF_LO(u1.x)+BF_LO(u2.x)+BF_LO(u3.x))
            + (BF_LO(u4.x)+BF_LO(u5.x)+BF_LO(u6.x)+BF_LO(u7.x));
        a1 += (BF_HI(u0.x)+BF_HI(u1.x)+BF_HI(u2.x)+BF_HI(u3.x))
            + (BF_HI(u4.x)+BF_HI(u5.x)+BF_HI(u6.x)+BF_HI(u7.x));
        a2 += (BF_LO(u0.y)+BF_LO(u1.y)+BF_LO(u2.y)+BF_LO(u3.y))
            + (BF_LO(u4.y)+BF_LO(u5.y)+BF_LO(u6.y)+BF_LO(u7.y));
        a3 += (BF_HI(u0.y)+BF_HI(u1.y)+BF_HI(u2.y)+BF_HI(u3.y))
            + (BF_HI(u4.y)+BF_HI(u5.y)+BF_HI(u6.y)+BF_HI(u7.y));
        a4 += (BF_LO(u0.z)+BF_LO(u1.z)+BF_LO(u2.z)+BF_LO(u3.z))
            + (BF_LO(u4.z)+BF_LO(u5.z)+BF_LO(u6.z)+BF_LO(u7.z));
        a5 += (BF_HI(u0.z)+BF_HI(u1.z)+BF_HI(u2.z)+BF_HI(u3.z))
            + (BF_HI(u4.z)+BF_HI(u5.z)+BF_HI(u6.z)+BF_HI(u7.z));
        a6 += (BF_LO(u0.w)+BF_LO(u1.w)+BF_LO(u2.w)+BF_LO(u3.w))
            + (BF_LO(u4.w)+BF_LO(u5.w)+BF_LO(u6.w)+BF_LO(u7.w));
        a7 += (BF_HI(u0.w)+BF_HI(u1.w)+BF_HI(u2.w)+BF_HI(u3.w))
            + (BF_HI(u4.w)+BF_HI(u5.w)+BF_HI(u6.w)+BF_HI(u7.w));
    }
    for (; j + 4 <= d; j += 4) {
        int s0 = sorted_src[start + j + 0];
        int s1 = sorted_src[start + j + 1];
        int s2 = sorted_src[start + j + 2];
        int s3 = sorted_src[start + j + 3];
        uint4 u0 = hb[s0 * 4 + q];
        uint4 u1 = hb[s1 * 4 + q];
        uint4 u2 = hb[s2 * 4 + q];
        uint4 u3 = hb[s3 * 4 + q];
        a0 += BF_LO(u0.x)+BF_LO(u1.x)+BF_LO(u2.x)+BF_LO(u3.x);
        a1 += BF_HI(u0.x)+BF_HI(u1.x)+BF_HI(u2.x)+BF_HI(u3.x);
        a2 += BF_LO(u0.y)+BF_LO(u1.y)+BF_LO(u2.y)+BF_LO(u3.y);
        a3 += BF_HI(u0.y)+BF_HI(u1.y)+BF_HI(u2.y)+BF_HI(u3.y);
        a4 += BF_LO(u0.z)+BF_LO(u1.z)+BF_LO(u2.z)+BF_LO(u3.z);
        a5 += BF_HI(u0.z)+BF_HI(u1.z)+BF_HI(u2.z)+BF_HI(u3.z);
        a6 += BF_LO(u0.w)+BF_LO(u1.w)+BF_LO(u2.w)+BF_LO(u3.w);
        a7 += BF_HI(u0.w)+BF_HI(u1.w)+BF_HI(u2.w)+BF_HI(u3.w);
    }
    for (; j < d; ++j) {
        uint4 u0 = hb[sorted_src[start + j] * 4 + q];
        a0 += BF_LO(u0.x); a1 += BF_HI(u0.x);
        a2 += BF_LO(u0.y); a3 += BF_HI(u0.y);
        a4 += BF_LO(u0.z); a5 += BF_HI(u0.z);
        a6 += BF_LO(u0.w); a7 += BF_HI(u0.w);
    }
    // merge raw lo-sums (agg2a) + hi-sums, apply 1/deg; stage h row
    if (valid) {
        float inv = 1.0f / ((d > 0) ? (float)d : 1.0f);
        const float4* ga = (const float4*)(agg2a + (size_t)n * 32 + q * 8);
        float4 v0 = ga[0], v1 = ga[1];
        float* sd = &sa[row * 33 + q * 8];
        sd[0] = (v0.x + a0) * inv; sd[1] = (v0.y + a1) * inv;
        sd[2] = (v0.z + a2) * inv; sd[3] = (v0.w + a3) * inv;
        sd[4] = (v1.x + a4) * inv; sd[5] = (v1.y + a5) * inv;
        sd[6] = (v1.z + a6) * inv; sd[7] = (v1.w + a7) * inv;
        const float4* gh = (const float4*)(hbuf + (size_t)n * 32 + q * 8);
        float4 h0 = gh[0], h1 = gh[1];
        float* se = &sh2[row * 33 + q * 8];
        se[0] = h0.x; se[1] = h0.y; se[2] = h0.z; se[3] = h0.w;
        se[4] = h1.x; se[5] = h1.y; se[6] = h1.z; se[7] = h1.w;
    }
    __syncthreads();

    // dense2: 4 lanes/node, lane q computes outputs q*8..q*8+7
    float acc[8];
    #pragma unroll
    for (int i = 0; i < 8; ++i) acc[i] = sb[q * 8 + i];
    for (int k = 0; k < 32; ++k) {
        float av = sa[row * 33 + k];
        float hv = sh2[row * 33 + k];
        const float4* wl4 = (const float4*)&swl[k * 32 + q * 8];
        const float4* wr4 = (const float4*)&swr[k * 32 + q * 8];
        float4 wla = wl4[0], wlb = wl4[1], wra = wr4[0], wrb = wr4[1];
        acc[0] += av * wla.x + hv * wra.x;
        acc[1] += av * wla.y + hv * wra.y;
        acc[2] += av * wla.z + hv * wra.z;
        acc[3] += av * wla.w + hv * wra.w;
        acc[4] += av * wlb.x + hv * wrb.x;
        acc[5] += av * wlb.y + hv * wrb.y;
        acc[6] += av * wlb.z + hv * wrb.z;
        acc[7] += av * wlb.w + hv * wrb.w;
    }
    float ss = 0.f;
    #pragma unroll
    for (int i = 0; i < 8; ++i) ss += acc[i] * acc[i];
    ss += __shfl_xor(ss, 1); ss += __shfl_xor(ss, 2);
    float invn = 1.f / fmaxf(sqrtf(ss), 1e-12f);
    float o0 = 0.f, o1 = 0.f;
    #pragma unroll
    for (int i = 0; i < 8; ++i) {
        float hv = fmaxf(acc[i] * invn, 0.f);
        int kk = q * 8 + i;
        o0 += hv * swo[kk * 2 + 0];
        o1 += hv * swo[kk * 2 + 1];
    }
    o0 += __shfl_xor(o0, 1); o0 += __shfl_xor(o0, 2);
    o1 += __shfl_xor(o1, 1); o1 += __shfl_xor(o1, 2);
    if (q == 0 && valid) {
        out[n * 2 + 0] = o0 + sbo[0];
        out[n * 2 + 1] = o1 + sbo[1];
    }
}

extern "C" void kernel_launch(void* const* d_in, const int* in_sizes, int n_in,
                              void* d_out, int out_size, void* d_ws, size_t ws_size,
                              hipStream_t stream) {
    const float* x    = (const float*)d_in[0];
    const int*   ei   = (const int*)d_in[1];
    const float* W1l  = (const float*)d_in[2];
    const float* b1   = (const float*)d_in[3];
    const float* W1r  = (const float*)d_in[4];
    const float* W2l  = (const float*)d_in[5];
    const float* b2   = (const float*)d_in[6];
    const float* W2r  = (const float*)d_in[7];
    const float* Wlin = (const float*)d_in[8];
    const float* blin = (const float*)d_in[9];
    float* out = (float*)d_out;

    const int N = in_sizes[0] / 14;
    const int E = in_sizes[1] / 2;
    const int* src = ei;
    const int* dst = ei + E;
    const int NBH = (N + 127) / 128;  // 782 half-buckets
    const int HALF = N / 2;

    char* ws = (char*)d_ws;
    size_t off = 0;
    auto alloc = [&](size_t bytes) -> void* {
        void* p = ws + off;
        off = (off + bytes + 255) & ~(size_t)255;
        return p;
    };
    int*            bcursor    = (int*)alloc((size_t)NBH * 4);
    unsigned*       part       = (unsigned*)alloc((size_t)NBH * CAPH * 4);  // dead after partitionB_sort
    int*            sorted_src = (int*)alloc((size_t)NBH * CAPH * 4);
    int*            deg        = (int*)alloc((size_t)N * 4);
    int*            offs       = (int*)alloc((size_t)N * 4);
    int*            nlo        = (int*)alloc((size_t)N * 4);
    unsigned short* xb         = (unsigned short*)alloc((size_t)N * 16 * 2);
    float*          hbuf       = (float*)alloc((size_t)N * 32 * 4);
    unsigned short* hb         = (unsigned short*)alloc((size_t)N * 32 * 2);
    float*          agg2a      = (float*)part;         // alias dead part buffer
    (void)ws_size; (void)n_in; (void)out_size;

    hipMemsetAsync(bcursor, 0, (size_t)NBH * 4, stream);
    partitionA<<<(E + CHA - 1) / CHA, 512, 0, stream>>>(
        x, xb, src, dst, bcursor, part, E, N, NBH);
    partitionB_sort<<<NBH, 1024, 0, stream>>>(
        part, bcursor, deg, offs, nlo, sorted_src, N, HALF);
    gather14_dense1<<<(N + 31) / 32, 256, 0, stream>>>(
        (const uint4*)xb, x, sorted_src, offs, deg, W1l, b1, W1r, hbuf, hb, N);
    gather32_p0<<<(N * 4 + 255) / 256, 256, 0, stream>>>(
        (const uint4*)hb, sorted_src, offs, nlo, (float4*)agg2a, N);
    gather32p1_dense2<<<(N + 63) / 64, 256, 0, stream>>>(
        (const uint4*)hb, sorted_src, offs, deg, nlo, agg2a, hbuf,
        W2l, b2, W2r, Wlin, blin, out, N);
}

// Round 4
// 267.644 us; speedup vs baseline: 1.1568x; 1.1568x over previous
//
#include <hip/hip_runtime.h>
#include <hip/hip_bf16.h>

// GraphSAGE (2x SAGEConv mean + normalize + relu, final linear) on MI355X.
// R19: revert partitionA to the LDS-staged counting sort + coalesced per-run
// copy-out (R18's direct global scatter caused 6x write amplification:
// WRITE_SIZE 32->189 MB, 48->96 us — partial-line scattered stores across
// 8 non-coherent XCD L2s). Keep R18's wins: cvt_x fused into partitionA,
// counts-based bcursor (memset init), gather32_p1+dense2 fused, 5 kernels.

#define CHA 16384   // edges per phase-A block
#define MAXBH 800   // max half-buckets (NBH = ceil(N/128) = 782)
#define CAPH 9728   // slots per 128-node half-bucket region (mean ~8.2K, ~17 sigma)

static __device__ __forceinline__ unsigned short f2bf(float f) {
    unsigned u = __float_as_uint(f);
    unsigned r = (u + 0x7FFFu + ((u >> 16) & 1u)) >> 16;   // RTN-even
    return (unsigned short)r;
}
#define BF_LO(u) __uint_as_float((u) << 16)
#define BF_HI(u) __uint_as_float((u) & 0xFFFF0000u)

// Phase A: per-block counting sort into LDS over 782 half-buckets (dst>>7),
// coalesced per-run copy-out (runs are 64-lane dense -> full lines to L2/HBM).
// bcursor holds per-bucket COUNTS (memset 0); global base = b*CAPH + reserved.
// Fused prologue converts x [N x 14] fp32 -> xb [N x 16] bf16.
__global__ __launch_bounds__(1024) void partitionA(
        const float* __restrict__ x, unsigned short* __restrict__ xb,
        const int* __restrict__ src, const int* __restrict__ dst,
        int* __restrict__ bcursor, unsigned* __restrict__ part,
        int E, int N, int NBH) {
    __shared__ unsigned pk[CHA];                       // 64 KB staging
    __shared__ int h[MAXBH], lofs[MAXBH], delta[MAXBH];  // 9.4 KB
    int t = threadIdx.x;
    int base = blockIdx.x * CHA;
    int end = base + CHA; if (end > E) end = E;
    int cnt = end - base;

    // fused cvt_x: x [N x 14] fp32 -> xb [N x 16] bf16 (rows padded to 32B)
    for (int i = blockIdx.x * 1024 + t; i < N * 16; i += gridDim.x * 1024) {
        int n = i >> 4, f = i & 15;
        float v = (f < 14) ? x[n * 14 + f] : 0.f;
        xb[i] = f2bf(v);
    }

    int ed[16], es[16], er[16];
    for (int i = t; i < NBH; i += 1024) h[i] = 0;
    __syncthreads();
    #pragma unroll
    for (int i = 0; i < 4; ++i) {
        int j = i * 4096 + t * 4;
        if (j + 4 <= cnt) {
            int4 d4 = *(const int4*)(dst + base + j);
            int4 s4 = *(const int4*)(src + base + j);
            ed[i*4+0] = d4.x; ed[i*4+1] = d4.y; ed[i*4+2] = d4.z; ed[i*4+3] = d4.w;
            es[i*4+0] = s4.x; es[i*4+1] = s4.y; es[i*4+2] = s4.z; es[i*4+3] = s4.w;
            er[i*4+0] = atomicAdd(&h[d4.x >> 7], 1);
            er[i*4+1] = atomicAdd(&h[d4.y >> 7], 1);
            er[i*4+2] = atomicAdd(&h[d4.z >> 7], 1);
            er[i*4+3] = atomicAdd(&h[d4.w >> 7], 1);
        } else {
            #pragma unroll
            for (int k = 0; k < 4; ++k) {
                if (j + k < cnt) {
                    ed[i*4+k] = dst[base + j + k];
                    es[i*4+k] = src[base + j + k];
                    er[i*4+k] = atomicAdd(&h[ed[i*4+k] >> 7], 1);
                } else ed[i*4+k] = -1;
            }
        }
    }
    __syncthreads();
    // wave-0 scan: 13 entries/lane covers up to 832 >= NBH
    if (t < 64) {
        int vals[13];
        int run = 0;
        int b13 = t * 13;
        #pragma unroll
        for (int i = 0; i < 13; ++i) {
            int idx = b13 + i;
            int xv = (idx < NBH) ? h[idx] : 0;
            run += xv;
            vals[i] = run;                           // local inclusive
        }
        int tot = run, sc = run;
        #pragma unroll
        for (int off = 1; off < 64; off <<= 1) {
            int nv = __shfl_up(sc, off);
            if (t >= off) sc += nv;
        }
        int excl = sc - tot;                         // wave-exclusive prefix
        #pragma unroll
        for (int i = 0; i < 13; ++i) {
            int idx = b13 + i;
            if (idx < NBH) {
                h[idx] = excl + vals[i];             // inclusive
                lofs[idx] = excl + (i ? vals[i - 1] : 0);  // exclusive
            }
        }
    }
    __syncthreads();
    if (t < NBH) {
        int excl = lofs[t];
        int v = h[t] - excl;
        int g = v ? atomicAdd(&bcursor[t], v) : 0;   // reserve run (count-based)
        delta[t] = t * CAPH + g - excl;              // global = delta + k
    }
    __syncthreads();
    #pragma unroll
    for (int i = 0; i < 16; ++i) {
        int d = ed[i];
        if (d >= 0) {
            int b = d >> 7;
            pk[lofs[b] + er[i]] = ((unsigned)(d & 127) << 24) | (unsigned)es[i];
        }
    }
    __syncthreads();
    // copy-out: h[b] (inclusive scan) is the end of bucket b's run
    int wid = t >> 6, lane = t & 63;
    for (int b = wid; b < NBH; b += 16) {
        int s = lofs[b];
        int e2 = h[b];
        int dlt = delta[b];
        int lim = (b + 1) * CAPH;                    // overflow guard (never hit)
        for (int k = s + lane; k < e2; k += 64) {
            int gidx = dlt + k;
            if (gidx < lim) part[gidx] = pk[k];
        }
    }
}

// Phase B sort: 256-key counting sort (key = dstLocal7*2 + (src>=HALF)),
// ranks from histogram atomics; sorted_src written linearly; per-node meta
// (deg/offs/nlo) written.
__global__ __launch_bounds__(1024) void partitionB_sort(
        const unsigned* __restrict__ part, const int* __restrict__ bcursor,
        int* __restrict__ deg, int* __restrict__ offs, int* __restrict__ nlo,
        int* __restrict__ sorted_src, int N, int HALF) {
    __shared__ int pk2[CAPH];                          // 38 KB staging
    __shared__ int hh[256], keyofs[256];
    __shared__ int sTot;
    int hbid = blockIdx.x;
    int t = threadIdx.x;
    int start = hbid * CAPH;
    int cc = bcursor[hbid];                            // per-bucket COUNT
    if (cc > CAPH) cc = CAPH;
    int end = start + cc;
    unsigned ce[10];
    int rk[10];
    if (t < 256) hh[t] = 0;
    __syncthreads();
    #pragma unroll
    for (int i = 0; i < 10; ++i) {
        int idx = start + t + i * 1024;
        unsigned p = 0xFFFFFFFFu;
        int r = 0;
        if (idx < end) {
            p = part[idx];
            int key = (int)(p >> 24) * 2 + (((int)(p & 0xFFFFFFu) < HALF) ? 0 : 1);
            r = atomicAdd(&hh[key], 1);
        }
        ce[i] = p;
        rk[i] = r;
    }
    __syncthreads();
    // wave-0 scan over the 256 keys (4/lane + shfl): writes keyofs = exclusive
    if (t < 64) {
        int b4 = t * 4;
        int v0 = hh[b4], v1 = hh[b4 + 1], v2 = hh[b4 + 2], v3 = hh[b4 + 3];
        int s1 = v0 + v1, s2 = s1 + v2, s3 = s2 + v3;
        int sc = s3;
        #pragma unroll
        for (int off = 1; off < 64; off <<= 1) {
            int nv = __shfl_up(sc, off);
            if (t >= off) sc += nv;
        }
        int excl = sc - s3;
        keyofs[b4]     = excl;
        keyofs[b4 + 1] = excl + v0;
        keyofs[b4 + 2] = excl + s1;
        keyofs[b4 + 3] = excl + s2;
        if (t == 63) sTot = excl + s3;
    }
    __syncthreads();
    if (t < 128) {
        int lo = hh[2 * t];
        int d = lo + hh[2 * t + 1];
        int excl = keyofs[2 * t];
        int node = hbid * 128 + t;
        if (node < N) {
            deg[node] = d;
            offs[node] = start + excl;
            nlo[node] = lo;
        }
    }
    #pragma unroll
    for (int i = 0; i < 10; ++i) {
        unsigned p = ce[i];
        if (p != 0xFFFFFFFFu) {
            int s = (int)(p & 0xFFFFFFu);
            int key = (int)(p >> 24) * 2 + ((s < HALF) ? 0 : 1);
            int pos = keyofs[key] + rk[i];
            if (pos < CAPH) pk2[pos] = s;
        }
    }
    __syncthreads();
    int tot = sTot; if (tot > CAPH) tot = CAPH;
    for (int i = t; i < tot; i += 1024)
        sorted_src[start + i] = pk2[i];
}

// Layer-1 gather + dense1 + normalize + relu. 256 threads = 32 nodes x
// 8 threads (4 edge-streams x 2 row-halves). All cross-thread exchange via
// __shfl within the aligned 8-lane node group.
__global__ __launch_bounds__(256) void gather14_dense1(
        const uint4* __restrict__ xb4, const float* __restrict__ x,
        const int* __restrict__ sorted_src, const int* __restrict__ offs,
        const int* __restrict__ deg,
        const float* __restrict__ W1l, const float* __restrict__ b1,
        const float* __restrict__ W1r,
        float* __restrict__ hbuf, unsigned short* __restrict__ hb, int N) {
    __shared__ float swl[448], swr[448], sb1[32];
    int t = threadIdx.x;
    for (int i = t; i < 448; i += 256) { swl[i] = W1l[i]; swr[i] = W1r[i]; }
    if (t < 32) sb1[t] = b1[t];
    __syncthreads();

    int node = blockIdx.x * 32 + (t >> 3);
    int sub = t & 7, ep = sub >> 1, half = sub & 1;
    int lanebase = (t & 63) & ~7;                      // node group base lane
    bool valid = node < N;
    int js = valid ? offs[node] : 0;
    int d  = valid ? deg[node] : 0;
    int je = js + d;
    float x0 = 0.f, x1 = 0.f;
    if (valid && sub < 7) {
        x0 = x[node * 14 + sub * 2];
        x1 = x[node * 14 + sub * 2 + 1];
    }

    float a[8] = {0,0,0,0,0,0,0,0};
    int j = js + ep;
    for (; j + 12 < je; j += 16) {                     // 4 edges/iter per stream
        int s0 = sorted_src[j], s1 = sorted_src[j + 4];
        int s2 = sorted_src[j + 8], s3 = sorted_src[j + 12];
        uint4 u0 = xb4[s0 * 2 + half], u1 = xb4[s1 * 2 + half];
        uint4 u2 = xb4[s2 * 2 + half], u3 = xb4[s3 * 2 + half];
        a[0] += (BF_LO(u0.x) + BF_LO(u1.x)) + (BF_LO(u2.x) + BF_LO(u3.x));
        a[1] += (BF_HI(u0.x) + BF_HI(u1.x)) + (BF_HI(u2.x) + BF_HI(u3.x));
        a[2] += (BF_LO(u0.y) + BF_LO(u1.y)) + (BF_LO(u2.y) + BF_LO(u3.y));
        a[3] += (BF_HI(u0.y) + BF_HI(u1.y)) + (BF_HI(u2.y) + BF_HI(u3.y));
        a[4] += (BF_LO(u0.z) + BF_LO(u1.z)) + (BF_LO(u2.z) + BF_LO(u3.z));
        a[5] += (BF_HI(u0.z) + BF_HI(u1.z)) + (BF_HI(u2.z) + BF_HI(u3.z));
        a[6] += (BF_LO(u0.w) + BF_LO(u1.w)) + (BF_LO(u2.w) + BF_LO(u3.w));
        a[7] += (BF_HI(u0.w) + BF_HI(u1.w)) + (BF_HI(u2.w) + BF_HI(u3.w));
    }
    for (; j + 4 < je; j += 8) {                       // 2 edges/iter per stream
        int s0 = sorted_src[j], s1 = sorted_src[j + 4];
        uint4 u0 = xb4[s0 * 2 + half], u1 = xb4[s1 * 2 + half];
        a[0] += BF_LO(u0.x) + BF_LO(u1.x);
        a[1] += BF_HI(u0.x) + BF_HI(u1.x);
        a[2] += BF_LO(u0.y) + BF_LO(u1.y);
        a[3] += BF_HI(u0.y) + BF_HI(u1.y);
        a[4] += BF_LO(u0.z) + BF_LO(u1.z);
        a[5] += BF_HI(u0.z) + BF_HI(u1.z);
        a[6] += BF_LO(u0.w) + BF_LO(u1.w);
        a[7] += BF_HI(u0.w) + BF_HI(u1.w);
    }
    for (; j < je; j += 4) {
        uint4 u0 = xb4[sorted_src[j] * 2 + half];
        a[0] += BF_LO(u0.x); a[1] += BF_HI(u0.x);
        a[2] += BF_LO(u0.y); a[3] += BF_HI(u0.y);
        a[4] += BF_LO(u0.z); a[5] += BF_HI(u0.z);
        a[6] += BF_LO(u0.w); a[7] += BF_HI(u0.w);
    }
    #pragma unroll
    for (int i = 0; i < 8; ++i) {
        a[i] += __shfl_xor(a[i], 2);                  // merge stream pairs
        a[i] += __shfl_xor(a[i], 4);                  // merge all 4 streams
    }

    // ---- dense1: each of 8 threads/node computes 4 of 32 outputs
    float inv = 1.0f / ((d > 0) ? (float)d : 1.0f);
    float acc[4];
    #pragma unroll
    for (int i = 0; i < 4; ++i) acc[i] = sb1[sub * 4 + i];
    #pragma unroll
    for (int k = 0; k < 14; ++k) {
        float ag = __shfl(a[k & 7], lanebase + (k >> 3)) * inv;   // half = k>=8
        float xv = __shfl((k & 1) ? x1 : x0, lanebase + (k >> 1));
        float4 wl = *(const float4*)&swl[k * 32 + sub * 4];
        float4 wr = *(const float4*)&swr[k * 32 + sub * 4];
        acc[0] += ag * wl.x + xv * wr.x;
        acc[1] += ag * wl.y + xv * wr.y;
        acc[2] += ag * wl.z + xv * wr.z;
        acc[3] += ag * wl.w + xv * wr.w;
    }
    float ss = 0.f;
    #pragma unroll
    for (int i = 0; i < 4; ++i) ss += acc[i] * acc[i];
    ss += __shfl_xor(ss, 1); ss += __shfl_xor(ss, 2); ss += __shfl_xor(ss, 4);
    float invn = 1.f / fmaxf(sqrtf(ss), 1e-12f);
    if (valid) {
        float hv[4];
        #pragma unroll
        for (int i = 0; i < 4; ++i) hv[i] = fmaxf(acc[i] * invn, 0.f);
        *(float4*)(hbuf + (size_t)node * 32 + sub * 4) =
            make_float4(hv[0], hv[1], hv[2], hv[3]);
        uint2 pb;
        pb.x = (unsigned)f2bf(hv[0]) | ((unsigned)f2bf(hv[1]) << 16);
        pb.y = (unsigned)f2bf(hv[2]) | ((unsigned)f2bf(hv[3]) << 16);
        *(uint2*)(hb + (size_t)node * 32 + sub * 4) = pb;
    }
}

// Layer-2 gather pass 0 (src < HALF; table half L2-resident): 8-deep unroll,
// writes RAW sums to agg2a.
__global__ __launch_bounds__(256) void gather32_p0(
        const uint4* __restrict__ hb, const int* __restrict__ sorted_src,
        const int* __restrict__ offs, const int* __restrict__ nlo,
        float4* __restrict__ agg2a, int N) {
    int idx = blockIdx.x * blockDim.x + threadIdx.x;
    int n = idx >> 2;
    if (n >= N) return;
    int q = idx & 3;
    int start = offs[n];
    int jend = nlo[n];
    float a0=0,a1=0,a2=0,a3=0,a4=0,a5=0,a6=0,a7=0;
    int j = 0;
    for (; j + 8 <= jend; j += 8) {
        int s0 = sorted_src[start + j + 0];
        int s1 = sorted_src[start + j + 1];
        int s2 = sorted_src[start + j + 2];
        int s3 = sorted_src[start + j + 3];
        int s4 = sorted_src[start + j + 4];
        int s5 = sorted_src[start + j + 5];
        int s6 = sorted_src[start + j + 6];
        int s7 = sorted_src[start + j + 7];
        uint4 u0 = hb[s0 * 4 + q];
        uint4 u1 = hb[s1 * 4 + q];
        uint4 u2 = hb[s2 * 4 + q];
        uint4 u3 = hb[s3 * 4 + q];
        uint4 u4 = hb[s4 * 4 + q];
        uint4 u5 = hb[s5 * 4 + q];
        uint4 u6 = hb[s6 * 4 + q];
        uint4 u7 = hb[s7 * 4 + q];
        a0 += (BF_LO(u0.x)+BF_LO(u1.x)+BF_LO(u2.x)+BF_LO(u3.x))
            + (BF_LO(u4.x)+BF_LO(u5.x)+BF_LO(u6.x)+BF_LO(u7.x));
        a1 += (BF_HI(u0.x)+BF_HI(u1.x)+BF_HI(u2.x)+BF_HI(u3.x))
            + (BF_HI(u4.x)+BF_HI(u5.x)+BF_HI(u6.x)+BF_HI(u7.x));
        a2 += (BF_LO(u0.y)+BF_LO(u1.y)+BF_LO(u2.y)+BF_LO(u3.y))
            + (BF_LO(u4.y)+BF_LO(u5.y)+BF_LO(u6.y)+BF_LO(u7.y));
        a3 += (BF_HI(u0.y)+BF_HI(u1.y)+BF_HI(u2.y)+BF_HI(u3.y))
            + (BF_HI(u4.y)+BF_HI(u5.y)+BF_HI(u6.y)+BF_HI(u7.y));
        a4 += (BF_LO(u0.z)+BF_LO(u1.z)+BF_LO(u2.z)+BF_LO(u3.z))
            + (BF_LO(u4.z)+BF_LO(u5.z)+BF_LO(u6.z)+BF_LO(u7.z));
        a5 += (BF_HI(u0.z)+BF_HI(u1.z)+BF_HI(u2.z)+BF_HI(u3.z))
            + (BF_HI(u4.z)+BF_HI(u5.z)+BF_HI(u6.z)+BF_HI(u7.z));
        a6 += (BF_LO(u0.w)+BF_LO(u1.w)+BF_LO(u2.w)+BF_LO(u3.w))
            + (BF_LO(u4.w)+BF_LO(u5.w)+BF_LO(u6.w)+BF_LO(u7.w));
        a7 += (BF_HI(u0.w)+BF_HI(u1.w)+BF_HI(u2.w)+BF_HI(u3.w))
            + (BF_HI(u4.w)+BF_HI(u5.w)+BF_HI(u6.w)+BF_HI(u7.w));
    }
    for (; j + 4 <= jend; j += 4) {
        int s0 = sorted_src[start + j + 0];
        int s1 = sorted_src[start + j + 1];
        int s2 = sorted_src[start + j + 2];
        int s3 = sorted_src[start + j + 3];
        uint4 u0 = hb[s0 * 4 + q];
        uint4 u1 = hb[s1 * 4 + q];
        uint4 u2 = hb[s2 * 4 + q];
        uint4 u3 = hb[s3 * 4 + q];
        a0 += BF_LO(u0.x)+BF_LO(u1.x)+BF_LO(u2.x)+BF_LO(u3.x);
        a1 += BF_HI(u0.x)+BF_HI(u1.x)+BF_HI(u2.x)+BF_HI(u3.x);
        a2 += BF_LO(u0.y)+BF_LO(u1.y)+BF_LO(u2.y)+BF_LO(u3.y);
        a3 += BF_HI(u0.y)+BF_HI(u1.y)+BF_HI(u2.y)+BF_HI(u3.y);
        a4 += BF_LO(u0.z)+BF_LO(u1.z)+BF_LO(u2.z)+BF_LO(u3.z);
        a5 += BF_HI(u0.z)+BF_HI(u1.z)+BF_HI(u2.z)+BF_HI(u3.z);
        a6 += BF_LO(u0.w)+BF_LO(u1.w)+BF_LO(u2.w)+BF_LO(u3.w);
        a7 += BF_HI(u0.w)+BF_HI(u1.w)+BF_HI(u2.w)+BF_HI(u3.w);
    }
    for (; j < jend; ++j) {
        uint4 u0 = hb[sorted_src[start + j] * 4 + q];
        a0 += BF_LO(u0.x); a1 += BF_HI(u0.x);
        a2 += BF_LO(u0.y); a3 += BF_HI(u0.y);
        a4 += BF_LO(u0.z); a5 += BF_HI(u0.z);
        a6 += BF_LO(u0.w); a7 += BF_HI(u0.w);
    }
    agg2a[n * 8 + q * 2 + 0] = make_float4(a0, a1, a2, a3);
    agg2a[n * 8 + q * 2 + 1] = make_float4(a4, a5, a6, a7);
}

// Layer-2 gather pass 1 (src >= HALF) FUSED with dense2 + final linear.
// 256 threads = 64 nodes x 4 lanes (q = feature quarter).
__global__ __launch_bounds__(256) void gather32p1_dense2(
        const uint4* __restrict__ hb, const int* __restrict__ sorted_src,
        const int* __restrict__ offs, const int* __restrict__ deg,
        const int* __restrict__ nlo, const float* __restrict__ agg2a,
        const float* __restrict__ hbuf,
        const float* __restrict__ W2l, const float* __restrict__ b2,
        const float* __restrict__ W2r, const float* __restrict__ Wlin,
        const float* __restrict__ blin, float* __restrict__ out, int N) {
    __shared__ float sa[64 * 33];                      // merged mean-agg rows
    __shared__ float sh2[64 * 33];                     // h rows
    __shared__ float swl[1024], swr[1024], swo[64], sb[32], sbo[2];
    int t = threadIdx.x;
    for (int i = t; i < 1024; i += 256) { swl[i] = W2l[i]; swr[i] = W2r[i]; }
    if (t < 64) swo[t] = Wlin[t];
    if (t < 32) sb[t] = b2[t];
    if (t < 2) sbo[t] = blin[t];

    int row = t >> 2, q = t & 3;
    int n = blockIdx.x * 64 + row;
    bool valid = n < N;
    int start = valid ? offs[n] : 0;
    int d = valid ? deg[n] : 0;
    int j = valid ? nlo[n] : 0;
    float a0=0,a1=0,a2=0,a3=0,a4=0,a5=0,a6=0,a7=0;
    for (; j + 8 <= d; j += 8) {
        int s0 = sorted_src[start + j + 0];
        int s1 = sorted_src[start + j + 1];
        int s2 = sorted_src[start + j + 2];
        int s3 = sorted_src[start + j + 3];
        int s4 = sorted_src[start + j + 4];
        int s5 = sorted_src[start + j + 5];
        int s6 = sorted_src[start + j + 6];
        int s7 = sorted_src[start + j + 7];
        uint4 u0 = hb[s0 * 4 + q];
        uint4 u1 = hb[s1 * 4 + q];
        uint4 u2 = hb[s2 * 4 + q];
        uint4 u3 = hb[s3 * 4 + q];
        uint4 u4 = hb[s4 * 4 + q];
        uint4 u5 = hb[s5 * 4 + q];
        uint4 u6 = hb[s6 * 4 + q];
        uint4 u7 = hb[s7 * 4 + q];
        a0 += (BF_LO(u0.x)+BF_LO(u1.x)+BF_LO(u2.x)+BF_LO(u3.x))
            + (BF_LO(u4.x)+BF_LO(u5.x)+BF_LO(u6.x)+BF_LO(u7.x));
        a1 += (BF_HI(u0.x)+BF_HI(u1.x)+BF_HI(u2.x)+BF_HI(u3.x))
            + (BF_HI(u4.x)+BF_HI(u5.x)+BF_HI(u6.x)+BF_HI(u7.x));
        a2 += (BF_LO(u0.y)+BF_LO(u1.y)+BF_LO(u2.y)+BF_LO(u3.y))
            + (BF_LO(u4.y)+BF_LO(u5.y)+BF_LO(u6.y)+BF_LO(u7.y));
        a3 += (BF_HI(u0.y)+BF_HI(u1.y)+BF_HI(u2.y)+BF_HI(u3.y))
            + (BF_HI(u4.y)+BF_HI(u5.y)+BF_HI(u6.y)+BF_HI(u7.y));
        a4 += (BF_LO(u0.z)+BF_LO(u1.z)+BF_LO(u2.z)+BF_LO(u3.z))
            + (BF_LO(u4.z)+BF_LO(u5.z)+BF_LO(u6.z)+BF_LO(u7.z));
        a5 += (BF_HI(u0.z)+BF_HI(u1.z)+BF_HI(u2.z)+BF_HI(u3.z))
            + (BF_HI(u4.z)+BF_HI(u5.z)+BF_HI(u6.z)+BF_HI(u7.z));
        a6 += (BF_LO(u0.w)+BF_LO(u1.w)+BF_LO(u2.w)+BF_LO(u3.w))
            + (BF_LO(u4.w)+BF_LO(u5.w)+BF_LO(u6.w)+BF_LO(u7.w));
        a7 += (BF_HI(u0.w)+BF_HI(u1.w)+BF_HI(u2.w)+BF_HI(u3.w))
            + (BF_HI(u4.w)+BF_HI(u5.w)+BF_HI(u6.w)+BF_HI(u7.w));
    }
    for (; j + 4 <= d; j += 4) {
        int s0 = sorted_src[start + j + 0];
        int s1 = sorted_src[start + j + 1];
        int s2 = sorted_src[start + j + 2];
        int s3 = sorted_src[start + j + 3];
        uint4 u0 = hb[s0 * 4 + q];
        uint4 u1 = hb[s1 * 4 + q];
        uint4 u2 = hb[s2 * 4 + q];
        uint4 u3 = hb[s3 * 4 + q];
        a0 += BF_LO(u0.x)+BF_LO(u1.x)+BF_LO(u2.x)+BF_LO(u3.x);
        a1 += BF_HI(u0.x)+BF_HI(u1.x)+BF_HI(u2.x)+BF_HI(u3.x);
        a2 += BF_LO(u0.y)+BF_LO(u1.y)+BF_LO(u2.y)+BF_LO(u3.y);
        a3 += BF_HI(u0.y)+BF_HI(u1.y)+BF_HI(u2.y)+BF_HI(u3.y);
        a4 += BF_LO(u0.z)+BF_LO(u1.z)+BF_LO(u2.z)+BF_LO(u3.z);
        a5 += BF_HI(u0.z)+BF_HI(u1.z)+BF_HI(u2.z)+BF_HI(u3.z);
        a6 += BF_LO(u0.w)+BF_LO(u1.w)+BF_LO(u2.w)+BF_LO(u3.w);
        a7 += BF_HI(u0.w)+BF_HI(u1.w)+BF_HI(u2.w)+BF_HI(u3.w);
    }
    for (; j < d; ++j) {
        uint4 u0 = hb[sorted_src[start + j] * 4 + q];
        a0 += BF_LO(u0.x); a1 += BF_HI(u0.x);
        a2 += BF_LO(u0.y); a3 += BF_HI(u0.y);
        a4 += BF_LO(u0.z); a5 += BF_HI(u0.z);
        a6 += BF_LO(u0.w); a7 += BF_HI(u0.w);
    }
    // merge raw lo-sums (agg2a) + hi-sums, apply 1/deg; stage h row
    if (valid) {
        float inv = 1.0f / ((d > 0) ? (float)d : 1.0f);
        const float4* ga = (const float4*)(agg2a + (size_t)n * 32 + q * 8);
        float4 v0 = ga[0], v1 = ga[1];
        float* sd = &sa[row * 33 + q * 8];
        sd[0] = (v0.x + a0) * inv; sd[1] = (v0.y + a1) * inv;
        sd[2] = (v0.z + a2) * inv; sd[3] = (v0.w + a3) * inv;
        sd[4] = (v1.x + a4) * inv; sd[5] = (v1.y + a5) * inv;
        sd[6] = (v1.z + a6) * inv; sd[7] = (v1.w + a7) * inv;
        const float4* gh = (const float4*)(hbuf + (size_t)n * 32 + q * 8);
        float4 h0 = gh[0], h1 = gh[1];
        float* se = &sh2[row * 33 + q * 8];
        se[0] = h0.x; se[1] = h0.y; se[2] = h0.z; se[3] = h0.w;
        se[4] = h1.x; se[5] = h1.y; se[6] = h1.z; se[7] = h1.w;
    }
    __syncthreads();

    // dense2: 4 lanes/node, lane q computes outputs q*8..q*8+7
    float acc[8];
    #pragma unroll
    for (int i = 0; i < 8; ++i) acc[i] = sb[q * 8 + i];
    for (int k = 0; k < 32; ++k) {
        float av = sa[row * 33 + k];
        float hv = sh2[row * 33 + k];
        const float4* wl4 = (const float4*)&swl[k * 32 + q * 8];
        const float4* wr4 = (const float4*)&swr[k * 32 + q * 8];
        float4 wla = wl4[0], wlb = wl4[1], wra = wr4[0], wrb = wr4[1];
        acc[0] += av * wla.x + hv * wra.x;
        acc[1] += av * wla.y + hv * wra.y;
        acc[2] += av * wla.z + hv * wra.z;
        acc[3] += av * wla.w + hv * wra.w;
        acc[4] += av * wlb.x + hv * wrb.x;
        acc[5] += av * wlb.y + hv * wrb.y;
        acc[6] += av * wlb.z + hv * wrb.z;
        acc[7] += av * wlb.w + hv * wrb.w;
    }
    float ss = 0.f;
    #pragma unroll
    for (int i = 0; i < 8; ++i) ss += acc[i] * acc[i];
    ss += __shfl_xor(ss, 1); ss += __shfl_xor(ss, 2);
    float invn = 1.f / fmaxf(sqrtf(ss), 1e-12f);
    float o0 = 0.f, o1 = 0.f;
    #pragma unroll
    for (int i = 0; i < 8; ++i) {
        float hv = fmaxf(acc[i] * invn, 0.f);
        int kk = q * 8 + i;
        o0 += hv * swo[kk * 2 + 0];
        o1 += hv * swo[kk * 2 + 1];
    }
    o0 += __shfl_xor(o0, 1); o0 += __shfl_xor(o0, 2);
    o1 += __shfl_xor(o1, 1); o1 += __shfl_xor(o1, 2);
    if (q == 0 && valid) {
        out[n * 2 + 0] = o0 + sbo[0];
        out[n * 2 + 1] = o1 + sbo[1];
    }
}

extern "C" void kernel_launch(void* const* d_in, const int* in_sizes, int n_in,
                              void* d_out, int out_size, void* d_ws, size_t ws_size,
                              hipStream_t stream) {
    const float* x    = (const float*)d_in[0];
    const int*   ei   = (const int*)d_in[1];
    const float* W1l  = (const float*)d_in[2];
    const float* b1   = (const float*)d_in[3];
    const float* W1r  = (const float*)d_in[4];
    const float* W2l  = (const float*)d_in[5];
    const float* b2   = (const float*)d_in[6];
    const float* W2r  = (const float*)d_in[7];
    const float* Wlin = (const float*)d_in[8];
    const float* blin = (const float*)d_in[9];
    float* out = (float*)d_out;

    const int N = in_sizes[0] / 14;
    const int E = in_sizes[1] / 2;
    const int* src = ei;
    const int* dst = ei + E;
    const int NBH = (N + 127) / 128;  // 782 half-buckets
    const int HALF = N / 2;

    char* ws = (char*)d_ws;
    size_t off = 0;
    auto alloc = [&](size_t bytes) -> void* {
        void* p = ws + off;
        off = (off + bytes + 255) & ~(size_t)255;
        return p;
    };
    int*            bcursor    = (int*)alloc((size_t)NBH * 4);
    unsigned*       part       = (unsigned*)alloc((size_t)NBH * CAPH * 4);  // dead after partitionB_sort
    int*            sorted_src = (int*)alloc((size_t)NBH * CAPH * 4);
    int*            deg        = (int*)alloc((size_t)N * 4);
    int*            offs       = (int*)alloc((size_t)N * 4);
    int*            nlo        = (int*)alloc((size_t)N * 4);
    unsigned short* xb         = (unsigned short*)alloc((size_t)N * 16 * 2);
    float*          hbuf       = (float*)alloc((size_t)N * 32 * 4);
    unsigned short* hb         = (unsigned short*)alloc((size_t)N * 32 * 2);
    float*          agg2a      = (float*)part;         // alias dead part buffer
    (void)ws_size; (void)n_in; (void)out_size;

    hipMemsetAsync(bcursor, 0, (size_t)NBH * 4, stream);
    partitionA<<<(E + CHA - 1) / CHA, 1024, 0, stream>>>(
        x, xb, src, dst, bcursor, part, E, N, NBH);
    partitionB_sort<<<NBH, 1024, 0, stream>>>(
        part, bcursor, deg, offs, nlo, sorted_src, N, HALF);
    gather14_dense1<<<(N + 31) / 32, 256, 0, stream>>>(
        (const uint4*)xb, x, sorted_src, offs, deg, W1l, b1, W1r, hbuf, hb, N);
    gather32_p0<<<(N * 4 + 255) / 256, 256, 0, stream>>>(
        (const uint4*)hb, sorted_src, offs, nlo, (float4*)agg2a, N);
    gather32p1_dense2<<<(N + 63) / 64, 256, 0, stream>>>(
        (const uint4*)hb, sorted_src, offs, deg, nlo, agg2a, hbuf,
        W2l, b2, W2r, Wlin, blin, out, N);
}

// Round 5
// 266.040 us; speedup vs baseline: 1.1638x; 1.0060x over previous
//
#include <hip/hip_runtime.h>
#include <hip/hip_bf16.h>

// GraphSAGE (2x SAGEConv mean + normalize + relu, final linear) on MI355X.
// R20: 5 kernels -> 3.
//  - partitionB re-fused with layer-1 gather+dense1 (gather indices from pk2
//    LDS, shfl-based dense1, 44 KB LDS) — kills the 26 MB sorted_src re-read
//    and one dispatch. R16/R17 showed fused==split on kernel time.
//  - gather32_p0 + p1 + dense2 merged: each node gathers [0,deg) in one pass.
//    The lo/hi sort key + full co-residency (1563 blocks, all resident) keeps
//    the 3.2 MB half-table L2 residency TEMPORALLY; agg2a round-trip (25.6 MB)
//    moves to registers. nlo dropped.
//  - partitionA unchanged (R19's LDS-staged copy-out + fused cvt_x).

#define CHA 16384   // edges per phase-A block
#define MAXBH 800   // max half-buckets (NBH = ceil(N/128) = 782)
#define CAPH 9728   // slots per 128-node half-bucket region (mean ~8.2K, ~17 sigma)

static __device__ __forceinline__ unsigned short f2bf(float f) {
    unsigned u = __float_as_uint(f);
    unsigned r = (u + 0x7FFFu + ((u >> 16) & 1u)) >> 16;   // RTN-even
    return (unsigned short)r;
}
#define BF_LO(u) __uint_as_float((u) << 16)
#define BF_HI(u) __uint_as_float((u) & 0xFFFF0000u)

// Phase A: per-block counting sort into LDS over 782 half-buckets (dst>>7),
// coalesced per-run copy-out. bcursor holds per-bucket COUNTS (memset 0).
// Fused prologue converts x [N x 14] fp32 -> xb [N x 16] bf16.
__global__ __launch_bounds__(1024) void partitionA(
        const float* __restrict__ x, unsigned short* __restrict__ xb,
        const int* __restrict__ src, const int* __restrict__ dst,
        int* __restrict__ bcursor, unsigned* __restrict__ part,
        int E, int N, int NBH) {
    __shared__ unsigned pk[CHA];                       // 64 KB staging
    __shared__ int h[MAXBH], lofs[MAXBH], delta[MAXBH];  // 9.4 KB
    int t = threadIdx.x;
    int base = blockIdx.x * CHA;
    int end = base + CHA; if (end > E) end = E;
    int cnt = end - base;

    // fused cvt_x: x [N x 14] fp32 -> xb [N x 16] bf16 (rows padded to 32B)
    for (int i = blockIdx.x * 1024 + t; i < N * 16; i += gridDim.x * 1024) {
        int n = i >> 4, f = i & 15;
        float v = (f < 14) ? x[n * 14 + f] : 0.f;
        xb[i] = f2bf(v);
    }

    int ed[16], es[16], er[16];
    for (int i = t; i < NBH; i += 1024) h[i] = 0;
    __syncthreads();
    #pragma unroll
    for (int i = 0; i < 4; ++i) {
        int j = i * 4096 + t * 4;
        if (j + 4 <= cnt) {
            int4 d4 = *(const int4*)(dst + base + j);
            int4 s4 = *(const int4*)(src + base + j);
            ed[i*4+0] = d4.x; ed[i*4+1] = d4.y; ed[i*4+2] = d4.z; ed[i*4+3] = d4.w;
            es[i*4+0] = s4.x; es[i*4+1] = s4.y; es[i*4+2] = s4.z; es[i*4+3] = s4.w;
            er[i*4+0] = atomicAdd(&h[d4.x >> 7], 1);
            er[i*4+1] = atomicAdd(&h[d4.y >> 7], 1);
            er[i*4+2] = atomicAdd(&h[d4.z >> 7], 1);
            er[i*4+3] = atomicAdd(&h[d4.w >> 7], 1);
        } else {
            #pragma unroll
            for (int k = 0; k < 4; ++k) {
                if (j + k < cnt) {
                    ed[i*4+k] = dst[base + j + k];
                    es[i*4+k] = src[base + j + k];
                    er[i*4+k] = atomicAdd(&h[ed[i*4+k] >> 7], 1);
                } else ed[i*4+k] = -1;
            }
        }
    }
    __syncthreads();
    // wave-0 scan: 13 entries/lane covers up to 832 >= NBH
    if (t < 64) {
        int vals[13];
        int run = 0;
        int b13 = t * 13;
        #pragma unroll
        for (int i = 0; i < 13; ++i) {
            int idx = b13 + i;
            int xv = (idx < NBH) ? h[idx] : 0;
            run += xv;
            vals[i] = run;                           // local inclusive
        }
        int tot = run, sc = run;
        #pragma unroll
        for (int off = 1; off < 64; off <<= 1) {
            int nv = __shfl_up(sc, off);
            if (t >= off) sc += nv;
        }
        int excl = sc - tot;                         // wave-exclusive prefix
        #pragma unroll
        for (int i = 0; i < 13; ++i) {
            int idx = b13 + i;
            if (idx < NBH) {
                h[idx] = excl + vals[i];             // inclusive
                lofs[idx] = excl + (i ? vals[i - 1] : 0);  // exclusive
            }
        }
    }
    __syncthreads();
    if (t < NBH) {
        int excl = lofs[t];
        int v = h[t] - excl;
        int g = v ? atomicAdd(&bcursor[t], v) : 0;   // reserve run (count-based)
        delta[t] = t * CAPH + g - excl;              // global = delta + k
    }
    __syncthreads();
    #pragma unroll
    for (int i = 0; i < 16; ++i) {
        int d = ed[i];
        if (d >= 0) {
            int b = d >> 7;
            pk[lofs[b] + er[i]] = ((unsigned)(d & 127) << 24) | (unsigned)es[i];
        }
    }
    __syncthreads();
    // copy-out: h[b] (inclusive scan) is the end of bucket b's run
    int wid = t >> 6, lane = t & 63;
    for (int b = wid; b < NBH; b += 16) {
        int s = lofs[b];
        int e2 = h[b];
        int dlt = delta[b];
        int lim = (b + 1) * CAPH;                    // overflow guard (never hit)
        for (int k = s + lane; k < e2; k += 64) {
            int gidx = dlt + k;
            if (gidx < lim) part[gidx] = pk[k];
        }
    }
}

// Phase B fused: 256-key counting sort (key = dstLocal7*2 + (src>=HALF)) ->
// pk2 LDS + sorted_src writeout + per-node meta, then LAYER-1 GATHER straight
// from pk2 (no global index re-read) + dense1 via shfl + normalize + relu.
__global__ __launch_bounds__(1024) void partitionB_fused(
        const unsigned* __restrict__ part, const int* __restrict__ bcursor,
        const uint4* __restrict__ xb4, const float* __restrict__ x,
        const float* __restrict__ W1l, const float* __restrict__ b1,
        const float* __restrict__ W1r,
        int* __restrict__ deg, int* __restrict__ offs,
        int* __restrict__ sorted_src, float* __restrict__ hbuf,
        unsigned short* __restrict__ hb, int N, int HALF) {
    __shared__ int pk2[CAPH];                          // 38 KB staging
    __shared__ int hh[256], keyofs[256];
    __shared__ int lstart[128], ldeg[128];
    __shared__ float swl[448], swr[448], sb1[32];
    __shared__ int sTot;
    int hbid = blockIdx.x;
    int t = threadIdx.x;
    int start = hbid * CAPH;
    int cc = bcursor[hbid];                            // per-bucket COUNT
    if (cc > CAPH) cc = CAPH;
    int end = start + cc;
    unsigned ce[10];
    int rk[10];
    if (t < 256) hh[t] = 0;
    if (t >= 512 && t < 960) { swl[t - 512] = W1l[t - 512]; swr[t - 512] = W1r[t - 512]; }
    else if (t >= 960 && t < 992) sb1[t - 960] = b1[t - 960];
    __syncthreads();
    #pragma unroll
    for (int i = 0; i < 10; ++i) {
        int idx = start + t + i * 1024;
        unsigned p = 0xFFFFFFFFu;
        int r = 0;
        if (idx < end) {
            p = part[idx];
            int key = (int)(p >> 24) * 2 + (((int)(p & 0xFFFFFFu) < HALF) ? 0 : 1);
            r = atomicAdd(&hh[key], 1);
        }
        ce[i] = p;
        rk[i] = r;
    }
    __syncthreads();
    // wave-0 scan over the 256 keys (4/lane + shfl): writes keyofs = exclusive
    if (t < 64) {
        int b4 = t * 4;
        int v0 = hh[b4], v1 = hh[b4 + 1], v2 = hh[b4 + 2], v3 = hh[b4 + 3];
        int s1 = v0 + v1, s2 = s1 + v2, s3 = s2 + v3;
        int sc = s3;
        #pragma unroll
        for (int off = 1; off < 64; off <<= 1) {
            int nv = __shfl_up(sc, off);
            if (t >= off) sc += nv;
        }
        int excl = sc - s3;
        keyofs[b4]     = excl;
        keyofs[b4 + 1] = excl + v0;
        keyofs[b4 + 2] = excl + s1;
        keyofs[b4 + 3] = excl + s2;
        if (t == 63) sTot = excl + s3;
    }
    __syncthreads();
    if (t < 128) {
        int lo = hh[2 * t];
        int d = lo + hh[2 * t + 1];
        int excl = keyofs[2 * t];
        lstart[t] = excl;
        ldeg[t] = d;
        int node = hbid * 128 + t;
        if (node < N) {
            deg[node] = d;
            offs[node] = start + excl;
        }
    }
    #pragma unroll
    for (int i = 0; i < 10; ++i) {
        unsigned p = ce[i];
        if (p != 0xFFFFFFFFu) {
            int s = (int)(p & 0xFFFFFFu);
            int key = (int)(p >> 24) * 2 + ((s < HALF) ? 0 : 1);
            int pos = keyofs[key] + rk[i];
            if (pos < CAPH) pk2[pos] = s;
        }
    }
    __syncthreads();
    int tot = sTot; if (tot > CAPH) tot = CAPH;
    for (int i = t; i < tot; i += 1024)
        sorted_src[start + i] = pk2[i];

    // ---- fused layer-1 gather: 8 threads/node = 4 edge-streams x 2 halves
    int node = t >> 3, sub = t & 7, ep = sub >> 1, half = sub & 1;
    int lanebase = (t & 63) & ~7;                      // node group base lane
    int gnode = hbid * 128 + node;
    bool valid = gnode < N;
    int js = lstart[node], d = ldeg[node];
    int je = js + d;
    float x0 = 0.f, x1 = 0.f;
    if (valid && sub < 7) {
        x0 = x[gnode * 14 + sub * 2];
        x1 = x[gnode * 14 + sub * 2 + 1];
    }

    float a[8] = {0,0,0,0,0,0,0,0};
    int j = js + ep;
    for (; j + 12 < je; j += 16) {                     // 4 edges/iter per stream
        int s0 = pk2[j], s1 = pk2[j + 4], s2 = pk2[j + 8], s3 = pk2[j + 12];
        uint4 u0 = xb4[s0 * 2 + half], u1 = xb4[s1 * 2 + half];
        uint4 u2 = xb4[s2 * 2 + half], u3 = xb4[s3 * 2 + half];
        a[0] += (BF_LO(u0.x) + BF_LO(u1.x)) + (BF_LO(u2.x) + BF_LO(u3.x));
        a[1] += (BF_HI(u0.x) + BF_HI(u1.x)) + (BF_HI(u2.x) + BF_HI(u3.x));
        a[2] += (BF_LO(u0.y) + BF_LO(u1.y)) + (BF_LO(u2.y) + BF_LO(u3.y));
        a[3] += (BF_HI(u0.y) + BF_HI(u1.y)) + (BF_HI(u2.y) + BF_HI(u3.y));
        a[4] += (BF_LO(u0.z) + BF_LO(u1.z)) + (BF_LO(u2.z) + BF_LO(u3.z));
        a[5] += (BF_HI(u0.z) + BF_HI(u1.z)) + (BF_HI(u2.z) + BF_HI(u3.z));
        a[6] += (BF_LO(u0.w) + BF_LO(u1.w)) + (BF_LO(u2.w) + BF_LO(u3.w));
        a[7] += (BF_HI(u0.w) + BF_HI(u1.w)) + (BF_HI(u2.w) + BF_HI(u3.w));
    }
    for (; j + 4 < je; j += 8) {                       // 2 edges/iter per stream
        int s0 = pk2[j], s1 = pk2[j + 4];
        uint4 u0 = xb4[s0 * 2 + half], u1 = xb4[s1 * 2 + half];
        a[0] += BF_LO(u0.x) + BF_LO(u1.x);
        a[1] += BF_HI(u0.x) + BF_HI(u1.x);
        a[2] += BF_LO(u0.y) + BF_LO(u1.y);
        a[3] += BF_HI(u0.y) + BF_HI(u1.y);
        a[4] += BF_LO(u0.z) + BF_LO(u1.z);
        a[5] += BF_HI(u0.z) + BF_HI(u1.z);
        a[6] += BF_LO(u0.w) + BF_LO(u1.w);
        a[7] += BF_HI(u0.w) + BF_HI(u1.w);
    }
    for (; j < je; j += 4) {
        uint4 u0 = xb4[pk2[j] * 2 + half];
        a[0] += BF_LO(u0.x); a[1] += BF_HI(u0.x);
        a[2] += BF_LO(u0.y); a[3] += BF_HI(u0.y);
        a[4] += BF_LO(u0.z); a[5] += BF_HI(u0.z);
        a[6] += BF_LO(u0.w); a[7] += BF_HI(u0.w);
    }
    #pragma unroll
    for (int i = 0; i < 8; ++i) {
        a[i] += __shfl_xor(a[i], 2);                  // merge stream pairs
        a[i] += __shfl_xor(a[i], 4);                  // merge all 4 streams
    }

    // ---- dense1: each of 8 threads/node computes 4 of 32 outputs
    float inv = 1.0f / ((d > 0) ? (float)d : 1.0f);
    float acc[4];
    #pragma unroll
    for (int i = 0; i < 4; ++i) acc[i] = sb1[sub * 4 + i];
    #pragma unroll
    for (int k = 0; k < 14; ++k) {
        float ag = __shfl(a[k & 7], lanebase + (k >> 3)) * inv;   // half = k>=8
        float xv = __shfl((k & 1) ? x1 : x0, lanebase + (k >> 1));
        float4 wl = *(const float4*)&swl[k * 32 + sub * 4];
        float4 wr = *(const float4*)&swr[k * 32 + sub * 4];
        acc[0] += ag * wl.x + xv * wr.x;
        acc[1] += ag * wl.y + xv * wr.y;
        acc[2] += ag * wl.z + xv * wr.z;
        acc[3] += ag * wl.w + xv * wr.w;
    }
    float ss = 0.f;
    #pragma unroll
    for (int i = 0; i < 4; ++i) ss += acc[i] * acc[i];
    ss += __shfl_xor(ss, 1); ss += __shfl_xor(ss, 2); ss += __shfl_xor(ss, 4);
    float invn = 1.f / fmaxf(sqrtf(ss), 1e-12f);
    if (valid) {
        float hv[4];
        #pragma unroll
        for (int i = 0; i < 4; ++i) hv[i] = fmaxf(acc[i] * invn, 0.f);
        *(float4*)(hbuf + (size_t)gnode * 32 + sub * 4) =
            make_float4(hv[0], hv[1], hv[2], hv[3]);
        uint2 pb;
        pb.x = (unsigned)f2bf(hv[0]) | ((unsigned)f2bf(hv[1]) << 16);
        pb.y = (unsigned)f2bf(hv[2]) | ((unsigned)f2bf(hv[3]) << 16);
        *(uint2*)(hb + (size_t)gnode * 32 + sub * 4) = pb;
    }
}

// Layer-2 gather (FULL list, lo-then-hi order from the sort key preserves
// half-table L2 residency temporally) + dense2 + normalize + relu + final
// linear. 256 threads = 64 nodes x 4 lanes (q = feature quarter).
__global__ __launch_bounds__(256) void gather32_dense2(
        const uint4* __restrict__ hb, const int* __restrict__ sorted_src,
        const int* __restrict__ offs, const int* __restrict__ deg,
        const float* __restrict__ hbuf,
        const float* __restrict__ W2l, const float* __restrict__ b2,
        const float* __restrict__ W2r, const float* __restrict__ Wlin,
        const float* __restrict__ blin, float* __restrict__ out, int N) {
    __shared__ float sa[64 * 33];                      // mean-agg rows
    __shared__ float sh2[64 * 33];                     // h rows
    __shared__ float swl[1024], swr[1024], swo[64], sb[32], sbo[2];
    int t = threadIdx.x;
    for (int i = t; i < 1024; i += 256) { swl[i] = W2l[i]; swr[i] = W2r[i]; }
    if (t < 64) swo[t] = Wlin[t];
    if (t < 32) sb[t] = b2[t];
    if (t < 2) sbo[t] = blin[t];

    int row = t >> 2, q = t & 3;
    int n = blockIdx.x * 64 + row;
    bool valid = n < N;
    int start = valid ? offs[n] : 0;
    int d = valid ? deg[n] : 0;
    float a0=0,a1=0,a2=0,a3=0,a4=0,a5=0,a6=0,a7=0;
    int j = 0;
    for (; j + 8 <= d; j += 8) {
        int s0 = sorted_src[start + j + 0];
        int s1 = sorted_src[start + j + 1];
        int s2 = sorted_src[start + j + 2];
        int s3 = sorted_src[start + j + 3];
        int s4 = sorted_src[start + j + 4];
        int s5 = sorted_src[start + j + 5];
        int s6 = sorted_src[start + j + 6];
        int s7 = sorted_src[start + j + 7];
        uint4 u0 = hb[s0 * 4 + q];
        uint4 u1 = hb[s1 * 4 + q];
        uint4 u2 = hb[s2 * 4 + q];
        uint4 u3 = hb[s3 * 4 + q];
        uint4 u4 = hb[s4 * 4 + q];
        uint4 u5 = hb[s5 * 4 + q];
        uint4 u6 = hb[s6 * 4 + q];
        uint4 u7 = hb[s7 * 4 + q];
        a0 += (BF_LO(u0.x)+BF_LO(u1.x)+BF_LO(u2.x)+BF_LO(u3.x))
            + (BF_LO(u4.x)+BF_LO(u5.x)+BF_LO(u6.x)+BF_LO(u7.x));
        a1 += (BF_HI(u0.x)+BF_HI(u1.x)+BF_HI(u2.x)+BF_HI(u3.x))
            + (BF_HI(u4.x)+BF_HI(u5.x)+BF_HI(u6.x)+BF_HI(u7.x));
        a2 += (BF_LO(u0.y)+BF_LO(u1.y)+BF_LO(u2.y)+BF_LO(u3.y))
            + (BF_LO(u4.y)+BF_LO(u5.y)+BF_LO(u6.y)+BF_LO(u7.y));
        a3 += (BF_HI(u0.y)+BF_HI(u1.y)+BF_HI(u2.y)+BF_HI(u3.y))
            + (BF_HI(u4.y)+BF_HI(u5.y)+BF_HI(u6.y)+BF_HI(u7.y));
        a4 += (BF_LO(u0.z)+BF_LO(u1.z)+BF_LO(u2.z)+BF_LO(u3.z))
            + (BF_LO(u4.z)+BF_LO(u5.z)+BF_LO(u6.z)+BF_LO(u7.z));
        a5 += (BF_HI(u0.z)+BF_HI(u1.z)+BF_HI(u2.z)+BF_HI(u3.z))
            + (BF_HI(u4.z)+BF_HI(u5.z)+BF_HI(u6.z)+BF_HI(u7.z));
        a6 += (BF_LO(u0.w)+BF_LO(u1.w)+BF_LO(u2.w)+BF_LO(u3.w))
            + (BF_LO(u4.w)+BF_LO(u5.w)+BF_LO(u6.w)+BF_LO(u7.w));
        a7 += (BF_HI(u0.w)+BF_HI(u1.w)+BF_HI(u2.w)+BF_HI(u3.w))
            + (BF_HI(u4.w)+BF_HI(u5.w)+BF_HI(u6.w)+BF_HI(u7.w));
    }
    for (; j + 4 <= d; j += 4) {
        int s0 = sorted_src[start + j + 0];
        int s1 = sorted_src[start + j + 1];
        int s2 = sorted_src[start + j + 2];
        int s3 = sorted_src[start + j + 3];
        uint4 u0 = hb[s0 * 4 + q];
        uint4 u1 = hb[s1 * 4 + q];
        uint4 u2 = hb[s2 * 4 + q];
        uint4 u3 = hb[s3 * 4 + q];
        a0 += BF_LO(u0.x)+BF_LO(u1.x)+BF_LO(u2.x)+BF_LO(u3.x);
        a1 += BF_HI(u0.x)+BF_HI(u1.x)+BF_HI(u2.x)+BF_HI(u3.x);
        a2 += BF_LO(u0.y)+BF_LO(u1.y)+BF_LO(u2.y)+BF_LO(u3.y);
        a3 += BF_HI(u0.y)+BF_HI(u1.y)+BF_HI(u2.y)+BF_HI(u3.y);
        a4 += BF_LO(u0.z)+BF_LO(u1.z)+BF_LO(u2.z)+BF_LO(u3.z);
        a5 += BF_HI(u0.z)+BF_HI(u1.z)+BF_HI(u2.z)+BF_HI(u3.z);
        a6 += BF_LO(u0.w)+BF_LO(u1.w)+BF_LO(u2.w)+BF_LO(u3.w);
        a7 += BF_HI(u0.w)+BF_HI(u1.w)+BF_HI(u2.w)+BF_HI(u3.w);
    }
    for (; j < d; ++j) {
        uint4 u0 = hb[sorted_src[start + j] * 4 + q];
        a0 += BF_LO(u0.x); a1 += BF_HI(u0.x);
        a2 += BF_LO(u0.y); a3 += BF_HI(u0.y);
        a4 += BF_LO(u0.z); a5 += BF_HI(u0.z);
        a6 += BF_LO(u0.w); a7 += BF_HI(u0.w);
    }
    // apply 1/deg; stage agg row + h row
    if (valid) {
        float inv = 1.0f / ((d > 0) ? (float)d : 1.0f);
        float* sd = &sa[row * 33 + q * 8];
        sd[0] = a0 * inv; sd[1] = a1 * inv; sd[2] = a2 * inv; sd[3] = a3 * inv;
        sd[4] = a4 * inv; sd[5] = a5 * inv; sd[6] = a6 * inv; sd[7] = a7 * inv;
        const float4* gh = (const float4*)(hbuf + (size_t)n * 32 + q * 8);
        float4 h0 = gh[0], h1 = gh[1];
        float* se = &sh2[row * 33 + q * 8];
        se[0] = h0.x; se[1] = h0.y; se[2] = h0.z; se[3] = h0.w;
        se[4] = h1.x; se[5] = h1.y; se[6] = h1.z; se[7] = h1.w;
    }
    __syncthreads();

    // dense2: 4 lanes/node, lane q computes outputs q*8..q*8+7
    float acc[8];
    #pragma unroll
    for (int i = 0; i < 8; ++i) acc[i] = sb[q * 8 + i];
    for (int k = 0; k < 32; ++k) {
        float av = sa[row * 33 + k];
        float hv = sh2[row * 33 + k];
        const float4* wl4 = (const float4*)&swl[k * 32 + q * 8];
        const float4* wr4 = (const float4*)&swr[k * 32 + q * 8];
        float4 wla = wl4[0], wlb = wl4[1], wra = wr4[0], wrb = wr4[1];
        acc[0] += av * wla.x + hv * wra.x;
        acc[1] += av * wla.y + hv * wra.y;
        acc[2] += av * wla.z + hv * wra.z;
        acc[3] += av * wla.w + hv * wra.w;
        acc[4] += av * wlb.x + hv * wrb.x;
        acc[5] += av * wlb.y + hv * wrb.y;
        acc[6] += av * wlb.z + hv * wrb.z;
        acc[7] += av * wlb.w + hv * wrb.w;
    }
    float ss = 0.f;
    #pragma unroll
    for (int i = 0; i < 8; ++i) ss += acc[i] * acc[i];
    ss += __shfl_xor(ss, 1); ss += __shfl_xor(ss, 2);
    float invn = 1.f / fmaxf(sqrtf(ss), 1e-12f);
    float o0 = 0.f, o1 = 0.f;
    #pragma unroll
    for (int i = 0; i < 8; ++i) {
        float hv = fmaxf(acc[i] * invn, 0.f);
        int kk = q * 8 + i;
        o0 += hv * swo[kk * 2 + 0];
        o1 += hv * swo[kk * 2 + 1];
    }
    o0 += __shfl_xor(o0, 1); o0 += __shfl_xor(o0, 2);
    o1 += __shfl_xor(o1, 1); o1 += __shfl_xor(o1, 2);
    if (q == 0 && valid) {
        out[n * 2 + 0] = o0 + sbo[0];
        out[n * 2 + 1] = o1 + sbo[1];
    }
}

extern "C" void kernel_launch(void* const* d_in, const int* in_sizes, int n_in,
                              void* d_out, int out_size, void* d_ws, size_t ws_size,
                              hipStream_t stream) {
    const float* x    = (const float*)d_in[0];
    const int*   ei   = (const int*)d_in[1];
    const float* W1l  = (const float*)d_in[2];
    const float* b1   = (const float*)d_in[3];
    const float* W1r  = (const float*)d_in[4];
    const float* W2l  = (const float*)d_in[5];
    const float* b2   = (const float*)d_in[6];
    const float* W2r  = (const float*)d_in[7];
    const float* Wlin = (const float*)d_in[8];
    const float* blin = (const float*)d_in[9];
    float* out = (float*)d_out;

    const int N = in_sizes[0] / 14;
    const int E = in_sizes[1] / 2;
    const int* src = ei;
    const int* dst = ei + E;
    const int NBH = (N + 127) / 128;  // 782 half-buckets
    const int HALF = N / 2;

    char* ws = (char*)d_ws;
    size_t off = 0;
    auto alloc = [&](size_t bytes) -> void* {
        void* p = ws + off;
        off = (off + bytes + 255) & ~(size_t)255;
        return p;
    };
    int*            bcursor    = (int*)alloc((size_t)NBH * 4);
    unsigned*       part       = (unsigned*)alloc((size_t)NBH * CAPH * 4);  // dead after partitionB
    int*            sorted_src = (int*)alloc((size_t)NBH * CAPH * 4);
    int*            deg        = (int*)alloc((size_t)N * 4);
    int*            offs       = (int*)alloc((size_t)N * 4);
    unsigned short* xb         = (unsigned short*)alloc((size_t)N * 16 * 2);
    float*          hbuf       = (float*)alloc((size_t)N * 32 * 4);
    unsigned short* hb         = (unsigned short*)alloc((size_t)N * 32 * 2);
    (void)ws_size; (void)n_in; (void)out_size;

    hipMemsetAsync(bcursor, 0, (size_t)NBH * 4, stream);
    partitionA<<<(E + CHA - 1) / CHA, 1024, 0, stream>>>(
        x, xb, src, dst, bcursor, part, E, N, NBH);
    partitionB_fused<<<NBH, 1024, 0, stream>>>(
        part, bcursor, (const uint4*)xb, x, W1l, b1, W1r,
        deg, offs, sorted_src, hbuf, hb, N, HALF);
    gather32_dense2<<<(N + 63) / 64, 256, 0, stream>>>(
        (const uint4*)hb, sorted_src, offs, deg, hbuf,
        W2l, b2, W2r, Wlin, blin, out, N);
}